// Round 17
// baseline (123.826 us; speedup 1.0000x reference)
//
#include <hip/hip_runtime.h>

typedef unsigned short u16;
typedef unsigned int u32;
typedef __bf16 bf16x8 __attribute__((ext_vector_type(8)));
typedef float f32x4 __attribute__((ext_vector_type(4)));
typedef u32 u32x4 __attribute__((ext_vector_type(4)));

#define MFMA(a, b, c) __builtin_amdgcn_mfma_f32_16x16x32_bf16(a, b, c, 0, 0, 0)

#define GLD16(gsrc, ldst)                                                          \
  __builtin_amdgcn_global_load_lds(                                                \
      (const __attribute__((address_space(1))) void*)(gsrc),                       \
      (__attribute__((address_space(3))) void*)(ldst), 16, 0, 0)

#if __has_builtin(__builtin_amdgcn_exp2f)
#define EXP2(x) __builtin_amdgcn_exp2f(x)
#else
#define EXP2(x) exp2f(x)
#endif

// native RNE converts (compiler emits v_cvt_pk_bf16_f32 / scalar cvt)
__device__ __forceinline__ u16 f2bf(float f) {
  return __builtin_bit_cast(u16, (__bf16)f);
}

__device__ __forceinline__ u32 pk2(float a, float b) {
  __bf16 x = (__bf16)a, y = (__bf16)b;
  return (u32)__builtin_bit_cast(u16, x) | ((u32)__builtin_bit_cast(u16, y) << 16);
}

__device__ __forceinline__ float bf2f(u16 u) {
  return __builtin_bit_cast(float, ((u32)u) << 16);
}

// -------- fused prep: X fp32->bf16 convert  +  weight transpose/convert --------
__global__ __launch_bounds__(256) void k_prep(
    const float* __restrict__ X, const float* __restrict__ Wq,
    const float* __restrict__ Wk, const float* __restrict__ Wv,
    const float* __restrict__ Wo, u16* __restrict__ Xb,
    u16* __restrict__ Wt, u16* __restrict__ Wot) {
  __shared__ u16 t[32][33];
  int bid = blockIdx.x;
  if (bid < 2048) {
    int i = bid * 256 + threadIdx.x;
    const float4* p = (const float4*)X + (size_t)i * 2;
    float4 a = p[0], b = p[1];
    uint4 o;
    o.x = pk2(a.x, a.y);
    o.y = pk2(a.z, a.w);
    o.z = pk2(b.x, b.y);
    o.w = pk2(b.z, b.w);
    *(uint4*)(Xb + (size_t)i * 8) = o;
    return;
  }
  bid -= 2048;
  const int k0 = (bid & 31) * 32, n0 = (bid >> 5) * 32;
  const int x = threadIdx.x & 31, y = threadIdx.x >> 5;
  const float* src = (n0 < 1024) ? Wq : (n0 < 2048) ? Wk : (n0 < 3072) ? Wv : Wo;
  const int ncol = n0 & 1023;
#pragma unroll
  for (int rr = 0; rr < 4; ++rr) {
    int kl = y + rr * 8;
    t[x][kl] = f2bf(src[(size_t)(k0 + kl) * 1024 + ncol + x]);
  }
  __syncthreads();
  u16* dst = (n0 < 3072) ? (Wt + (size_t)n0 * 1024) : (Wot + (size_t)(n0 - 3072) * 1024);
#pragma unroll
  for (int rr = 0; rr < 4; ++rr) {
    int nl = y + rr * 8;
    dst[(size_t)nl * 1024 + k0 + x] = t[nl][x];
  }
}

// ============================================================================
// GEMM structure: BK=32, double-buffered LDS, ONE barrier per K-step (R6 proven).
// LDS tile [*][32] u16, 4 granules of 8 u16 per row.
// Swizzle: LDS slot s of row r holds global granule s ^ ((r>>1)&3).
// ============================================================================

// ---------------- QKV projection GEMM (R6 exact: 128x128) ----------------
// Q scaled by 0.125*log2(e) (exp2-domain softmax), layout [bh][s][d];
// K layout [bh][s][d]; V TRANSPOSED [bh][d][s]
__global__ __launch_bounds__(256) void k_gemm_qkv(const u16* __restrict__ A_,
                                                  const u16* __restrict__ Bt,
                                                  u16* __restrict__ Q,
                                                  u16* __restrict__ K,
                                                  u16* __restrict__ Vt) {
  __shared__ __align__(16) u16 As[2][128 * 32];
  __shared__ __align__(16) u16 Bs[2][128 * 32];
  const int tid = threadIdx.x;
  const int w = tid >> 6, l = tid & 63;
  const int lr = l & 15, lg = l >> 4;
  // XCD-aware swizzle (grid 24x32 = 768, 768%8==0 -> bijective)
  const int lin = blockIdx.y * 24 + blockIdx.x;
  const int swz = (lin & 7) * 96 + (lin >> 3);
  const int tM = (swz / 24) * 128, tN = (swz % 24) * 128;
  const int wr = w >> 1, wc = w & 1;
  const int bufsel = tN >> 10;  // 0=Q, 1=K, 2=V

  const int srow = l >> 2;
  const int scol = (((l & 3) ^ ((l >> 3) & 3)) << 3);  // pre-swizzled src granule
  const u16* Ag = A_ + (size_t)(tM + srow) * 1024 + scol;
  const u16* Bg = Bt + (size_t)(tN + srow) * 1024 + scol;
  const int rs = (lr >> 1) & 3;  // read-side swizzle

#define STAGE_QKV(buf, kk)                                                   \
  {                                                                          \
    GLD16(Ag + (size_t)(w * 16) * 1024 + (kk), &As[buf][(w * 16) * 32]);     \
    GLD16(Ag + (size_t)(64 + w * 16) * 1024 + (kk), &As[buf][(64 + w * 16) * 32]); \
    GLD16(Bg + (size_t)(w * 16) * 1024 + (kk), &Bs[buf][(w * 16) * 32]);     \
    GLD16(Bg + (size_t)(64 + w * 16) * 1024 + (kk), &Bs[buf][(64 + w * 16) * 32]); \
  }

  f32x4 acc[4][4] = {};
  STAGE_QKV(0, 0)
  __syncthreads();
  int cur = 0;

  if (bufsel < 2) {
    // ---- swapped-operand loop: acc rows = N(d)-dir via (lg,j), cols = M(s) via lr
    for (int t = 0; t < 32; ++t) {
      if (t < 31) STAGE_QKV(cur ^ 1, (t + 1) * 32)
      const u16* Ac = &As[cur][0];
      const u16* Bc = &Bs[cur][0];
      bf16x8 a[4], b[4];
#pragma unroll
      for (int m = 0; m < 4; ++m)
        a[m] = *(const bf16x8*)(Ac + (wr * 64 + m * 16 + lr) * 32 + ((lg ^ rs) << 3));
#pragma unroll
      for (int n = 0; n < 4; ++n)
        b[n] = *(const bf16x8*)(Bc + (wc * 64 + n * 16 + lr) * 32 + ((lg ^ rs) << 3));
#pragma unroll
      for (int m = 0; m < 4; ++m)
#pragma unroll
        for (int n = 0; n < 4; ++n) acc[m][n] = MFMA(b[n], a[m], acc[m][n]);
      __syncthreads();
      cur ^= 1;
    }
    u16* dst = bufsel ? K : Q;
    // 0.125 * log2(e): exp2-domain scores
    const float sc = bufsel ? 1.0f : 0.180336880111124f;
#pragma unroll
    for (int m = 0; m < 4; ++m) {
      int s = tM + wr * 64 + m * 16 + lr;
      int b_ = s >> 11, sr2 = s & 2047;
#pragma unroll
      for (int n = 0; n < 4; ++n) {
        int c2 = (tN + wc * 64 + n * 16 + lg * 4) & 1023;
        int h = c2 >> 6, d = c2 & 63;
        uint2 val;
        val.x = pk2(acc[m][n][0] * sc, acc[m][n][1] * sc);
        val.y = pk2(acc[m][n][2] * sc, acc[m][n][3] * sc);
        *(uint2*)(dst + ((size_t)(b_ * 16 + h) * 2048 + sr2) * 64 + d) = val;
      }
    }
  } else {
    // ---- normal loop: acc rows = M(s)-dir via (lg,j), cols = N(d) via lr
    for (int t = 0; t < 32; ++t) {
      if (t < 31) STAGE_QKV(cur ^ 1, (t + 1) * 32)
      const u16* Ac = &As[cur][0];
      const u16* Bc = &Bs[cur][0];
      bf16x8 a[4], b[4];
#pragma unroll
      for (int m = 0; m < 4; ++m)
        a[m] = *(const bf16x8*)(Ac + (wr * 64 + m * 16 + lr) * 32 + ((lg ^ rs) << 3));
#pragma unroll
      for (int n = 0; n < 4; ++n)
        b[n] = *(const bf16x8*)(Bc + (wc * 64 + n * 16 + lr) * 32 + ((lg ^ rs) << 3));
#pragma unroll
      for (int m = 0; m < 4; ++m)
#pragma unroll
        for (int n = 0; n < 4; ++n) acc[m][n] = MFMA(a[m], b[n], acc[m][n]);
      __syncthreads();
      cur ^= 1;
    }
    // V transposed: Vt[(bh*64 + d)][s], 4 consecutive s (=j) packed into 8B
#pragma unroll
    for (int m = 0; m < 4; ++m) {
      int r0 = tM + wr * 64 + m * 16 + lg * 4;
      int b_ = r0 >> 11, s0 = r0 & 2047;
#pragma unroll
      for (int n = 0; n < 4; ++n) {
        int c2 = (tN + wc * 64 + n * 16 + lr) & 1023;
        int h = c2 >> 6, d = c2 & 63;
        uint2 val;
        val.x = pk2(acc[m][n][0], acc[m][n][1]);
        val.y = pk2(acc[m][n][2], acc[m][n][3]);
        *(uint2*)(Vt + ((size_t)(b_ * 16 + h) * 64 + d) * 2048 + s0) = val;
      }
    }
  }
#undef STAGE_QKV
}

// ---------------- causal flash attention (KV-split flash-decode) ----------------
// R9 structure with P kept ENTIRELY in registers: MFMA k-dim permutation
// pi(8*lg+e) = 16*(e>=4) + 4*lg + (e&3) makes the PV B-operand the lane's own
// st[] values (zero LDS bounce, zero cross-lane); V A-operand reads 4x b64 per n
// at granules {g0, 2+g0, 4+g0, 6+g0} (g0=lg>>1), half lg&1, slot G^(row&7).
// Ps buffer removed: LDS 32 KB -> 5 blocks/CU. l_run kept as per-lane partial
// (m_run is row-uniform), reduced once in the epilogue.
// Defer-max (T13) + setprio (T5).
__global__ __launch_bounds__(256, 5) void k_attn(const u16* __restrict__ Q,
                                                 const u16* __restrict__ Kg,
                                                 const u16* __restrict__ Vtg,
                                                 u16* __restrict__ AO,
                                                 u16* __restrict__ PO,
                                                 float* __restrict__ ML) {
  __shared__ __align__(16) u16 Ks[2][64 * 64];
  __shared__ __align__(16) u16 Vs[2][64 * 64];
  const int tid = threadIdx.x;
  const int w = tid >> 6, l = tid & 63;
  const int lr = l & 15, lg = l >> 4;

  const int idx = blockIdx.x;
  const int bh = idx & 31;
  const int g = idx >> 5;
  int qt, c0;
  if (g < 16) { qt = 16 + g; c0 = 0; }
  else if (g < 32) { qt = 31 - (g - 16); c0 = 1; }
  else { qt = 15 - (g - 32); c0 = 0; }
  const int nkt = (qt < 16) ? (qt + 1) : (c0 == 0 ? 16 : qt - 15);
  const bool hasdiag = (qt < 16) || (c0 == 1);
  const int q0 = qt * 64;

  const u16* Qp = Q + (size_t)bh * 2048 * 64;
  const u16* Kp = Kg + (size_t)bh * 2048 * 64;
  const u16* Vp = Vtg + (size_t)bh * 64 * 2048;

  const int qrow = q0 + w * 16 + lr;
  bf16x8 qa0 = *(const bf16x8*)(Qp + (size_t)qrow * 64 + lg * 8);
  bf16x8 qa1 = *(const bf16x8*)(Qp + (size_t)qrow * 64 + 32 + lg * 8);

  // oacc[n][j] = O[q = lr][d = n*16 + lg*4 + j]  (swapped-PV layout)
  f32x4 oacc[4] = {};
  float m_run = -1e30f, l_run = 0.f;  // l_run: per-lane partial (reduced at end)

  const int srow = l >> 3;                // row-in-chunk 0..7
  const int scol = ((l & 7) ^ srow) * 8;  // pre-swizzled source column (u16)
  const int sw = (lr & 7) << 3;           // K read-side swizzle (u16 units)
  const int vr7 = lr & 7;                 // row&7 for V slot calc
  const int vh = (lg & 1) * 4;            // half-granule offset (u16)
  const int g0 = lg >> 1;                 // base granule for V b64 reads

  // per-lane staging pointers (advance by one K-tile per iteration)
  const u16* kptr = Kp + ((size_t)c0 * 1024 + srow) * 64 + scol;
  const u16* vptr = Vp + (size_t)srow * 2048 + c0 * 1024 + scol;

  // prologue: stage tile 0 into buf 0
#pragma unroll
  for (int j = 0; j < 2; ++j) {
    int base = j * 32 + w * 8;
    GLD16(kptr + base * 64, &Ks[0][base * 64]);
    GLD16(vptr + (size_t)base * 2048, &Vs[0][base * 64]);
  }
  kptr += 4096;
  vptr += 64;
  __syncthreads();

  int cur = 0;

#define ATTN_TILE(DOPRE, DOMASK)                                                   \
  {                                                                                \
    if (DOPRE) {                                                                   \
      _Pragma("unroll") for (int j = 0; j < 2; ++j) {                              \
        int base = j * 32 + w * 8;                                                 \
        GLD16(kptr + base * 64, &Ks[cur ^ 1][base * 64]);                          \
        GLD16(vptr + (size_t)base * 2048, &Vs[cur ^ 1][base * 64]);                \
      }                                                                            \
      kptr += 4096;                                                                \
      vptr += 64;                                                                  \
    }                                                                              \
    f32x4 st[4];                                                                   \
    __builtin_amdgcn_s_setprio(1);                                                 \
    _Pragma("unroll") for (int n = 0; n < 4; ++n) {                                \
      const u16* kr = &Ks[cur][(n * 16 + lr) * 64];                                \
      bf16x8 kb0 = *(const bf16x8*)(kr + ((lg << 3) ^ sw));                        \
      bf16x8 kb1 = *(const bf16x8*)(kr + (((4 + lg) << 3) ^ sw));                  \
      f32x4 z = {0.f, 0.f, 0.f, 0.f};                                              \
      z = MFMA(kb0, qa0, z);                                                       \
      z = MFMA(kb1, qa1, z);                                                       \
      st[n] = z;                                                                   \
    }                                                                              \
    __builtin_amdgcn_s_setprio(0);                                                 \
    float mx = -1e30f;                                                             \
    _Pragma("unroll") for (int n = 0; n < 4; ++n)                                  \
        _Pragma("unroll") for (int j = 0; j < 4; ++j) {                            \
      float s = st[n][j];                                                          \
      if (DOMASK && (n * 16 + lg * 4 + j) > (w * 16 + lr)) s = -1e30f;             \
      st[n][j] = s;                                                                \
      mx = fmaxf(mx, s);                                                           \
    }                                                                              \
    mx = fmaxf(mx, __shfl_xor(mx, 16, 64));                                        \
    mx = fmaxf(mx, __shfl_xor(mx, 32, 64));                                        \
    const bool grow = __any(mx > m_run + 8.0f);  /* defer-max THR=8 */             \
    float mnew = grow ? fmaxf(m_run, mx) : m_run;                                  \
    float rsum = 0.f;                                                              \
    _Pragma("unroll") for (int n = 0; n < 4; ++n)                                  \
        _Pragma("unroll") for (int j = 0; j < 4; ++j) {                            \
      float p = EXP2(st[n][j] - mnew);                                             \
      st[n][j] = p;                                                                \
      rsum += p;                                                                   \
    }                                                                              \
    if (grow) {                                                                    \
      float fsc = EXP2(m_run - mnew);                                              \
      l_run = l_run * fsc + rsum;                                                  \
      m_run = mnew;                                                                \
      _Pragma("unroll") for (int n = 0; n < 4; ++n)                                \
          _Pragma("unroll") for (int j = 0; j < 4; ++j) oacc[n][j] *= fsc;         \
    } else {                                                                       \
      l_run += rsum;                                                               \
    }                                                                              \
    /* P stays in registers: pa0 = {st0,st1}, pa1 = {st2,st3} (k-dim permuted) */  \
    u32x4 tp0, tp1;                                                                \
    tp0.x = pk2(st[0][0], st[0][1]);                                               \
    tp0.y = pk2(st[0][2], st[0][3]);                                               \
    tp0.z = pk2(st[1][0], st[1][1]);                                               \
    tp0.w = pk2(st[1][2], st[1][3]);                                               \
    tp1.x = pk2(st[2][0], st[2][1]);                                               \
    tp1.y = pk2(st[2][2], st[2][3]);                                               \
    tp1.z = pk2(st[3][0], st[3][1]);                                               \
    tp1.w = pk2(st[3][2], st[3][3]);                                               \
    bf16x8 pa0 = __builtin_bit_cast(bf16x8, tp0);                                  \
    bf16x8 pa1 = __builtin_bit_cast(bf16x8, tp1);                                  \
    __builtin_amdgcn_s_setprio(1);                                                 \
    _Pragma("unroll") for (int n = 0; n < 4; ++n) {                                \
      const u16* vr = &Vs[cur][(n * 16 + lr) * 64];                                \
      uint2 v00 = *(const uint2*)(vr + (((g0 ^ vr7) << 3) + vh));                  \
      uint2 v01 = *(const uint2*)(vr + ((((2 + g0) ^ vr7) << 3) + vh));            \
      uint2 v10 = *(const uint2*)(vr + ((((4 + g0) ^ vr7) << 3) + vh));            \
      uint2 v11 = *(const uint2*)(vr + ((((6 + g0) ^ vr7) << 3) + vh));            \
      u32x4 tv0, tv1;                                                              \
      tv0.x = v00.x; tv0.y = v00.y; tv0.z = v01.x; tv0.w = v01.y;                  \
      tv1.x = v10.x; tv1.y = v10.y; tv1.z = v11.x; tv1.w = v11.y;                  \
      oacc[n] = MFMA(__builtin_bit_cast(bf16x8, tv0), pa0, oacc[n]);               \
      oacc[n] = MFMA(__builtin_bit_cast(bf16x8, tv1), pa1, oacc[n]);               \
    }                                                                              \
    __builtin_amdgcn_s_setprio(0);                                                 \
  }

  // main loop: no masking, always prefetch
  for (int it = 0; it < nkt - 1; ++it) {
    ATTN_TILE(true, false);
    __syncthreads();
    cur ^= 1;
  }
  // tail: no prefetch; mask only if this chunk contains the diagonal
  if (hasdiag) {
    ATTN_TILE(false, true);
  } else {
    ATTN_TILE(false, false);
  }
#undef ATTN_TILE

  // reduce per-lane l partials across the row's 4 lanes (m_run was row-uniform)
  float lsum = l_run;
  lsum += __shfl_xor(lsum, 16, 64);
  lsum += __shfl_xor(lsum, 32, 64);

  if (qt < 16) {
    const int b_ = bh >> 4, h = bh & 15;
    const float linv = 1.0f / lsum;  // lane-local (q = lr)
    const int s = q0 + w * 16 + lr;
    u16* dst = AO + ((size_t)(b_ * 2048 + s)) * 1024 + h * 64 + lg * 4;
#pragma unroll
    for (int n = 0; n < 4; ++n) {
      uint2 val;
      val.x = pk2(oacc[n][0] * linv, oacc[n][1] * linv);
      val.y = pk2(oacc[n][2] * linv, oacc[n][3] * linv);
      *(uint2*)(dst + n * 16) = val;
    }
  } else {
    const int p = (bh * 16 + (qt - 16)) * 2 + c0;
    u16* po = PO + (size_t)p * 4096 + (size_t)(w * 16 + lr) * 64 + lg * 4;
#pragma unroll
    for (int n = 0; n < 4; ++n) {
      uint2 val;
      val.x = pk2(oacc[n][0], oacc[n][1]);
      val.y = pk2(oacc[n][2], oacc[n][3]);
      *(uint2*)(po + n * 16) = val;
    }
    if (lg == 0) {
      ML[(size_t)p * 128 + (w * 16 + lr)] = m_run;
      ML[(size_t)p * 128 + 64 + (w * 16 + lr)] = lsum;
    }
  }
}

// ---------------- combine partials for qt >= 16 (base-2 m/l) ----------------
__global__ __launch_bounds__(256) void k_combine(const u16* __restrict__ PO,
                                                 const float* __restrict__ ML,
                                                 u16* __restrict__ AO) {
  const int blk = blockIdx.x;  // bh*16 + (qt-16)
  const int bh = blk >> 4, qt = 16 + (blk & 15);
  const int row = threadIdx.x >> 2;
  const int dseg = (threadIdx.x & 3) * 16;
  const size_t p0 = (size_t)blk * 2;
  const float m0 = ML[p0 * 128 + row], l0 = ML[p0 * 128 + 64 + row];
  const float m1 = ML[p0 * 128 + 128 + row], l1 = ML[p0 * 128 + 192 + row];
  const float M = fmaxf(m0, m1);
  float w0 = EXP2(m0 - M), w1 = EXP2(m1 - M);
  const float inv = 1.0f / (l0 * w0 + l1 * w1);
  w0 *= inv;
  w1 *= inv;
  const u16* o0 = PO + p0 * 4096 + (size_t)row * 64 + dseg;
  const u16* o1 = o0 + 4096;
  const int b_ = bh >> 4, h = bh & 15;
  u16* dst = AO + ((size_t)(b_ * 2048 + qt * 64 + row)) * 1024 + h * 64 + dseg;
#pragma unroll
  for (int half = 0; half < 2; ++half) {
    uint4 a = *(const uint4*)(o0 + half * 8);
    uint4 b = *(const uint4*)(o1 + half * 8);
    u32 aw[4] = {a.x, a.y, a.z, a.w};
    u32 bw[4] = {b.x, b.y, b.z, b.w};
    uint4 o;
    u32 ow[4];
#pragma unroll
    for (int i = 0; i < 4; ++i) {
      float r0 = bf2f((u16)(aw[i] & 0xffffu)) * w0 + bf2f((u16)(bw[i] & 0xffffu)) * w1;
      float r1 = bf2f((u16)(aw[i] >> 16)) * w0 + bf2f((u16)(bw[i] >> 16)) * w1;
      ow[i] = pk2(r0, r1);
    }
    o.x = ow[0]; o.y = ow[1]; o.z = ow[2]; o.w = ow[3];
    *(uint4*)(dst + half * 8) = o;
  }
}

// ---------------- output projection GEMM (fp32 out) ----------------
// 128x64 tiles, BK=32 dbuf, swapped operands -> float4 stores (R6 proven).
__global__ __launch_bounds__(256) void k_gemm_out(const u16* __restrict__ A_,
                                                  const u16* __restrict__ Bt,
                                                  float* __restrict__ out) {
  __shared__ __align__(16) u16 As[2][128 * 32];
  __shared__ __align__(16) u16 Bs[2][64 * 32];
  const int tid = threadIdx.x;
  const int w = tid >> 6, l = tid & 63;
  const int lr = l & 15, lg = l >> 4;
  // XCD swizzle (grid 16x32 = 512)
  const int lin = blockIdx.y * 16 + blockIdx.x;
  const int swz = (lin & 7) * 64 + (lin >> 3);
  const int tM = (swz / 16) * 128, tN = (swz % 16) * 64;

  const int srow = l >> 2;
  const int scol = (((l & 3) ^ ((l >> 3) & 3)) << 3);
  const u16* Ag = A_ + (size_t)(tM + srow) * 1024 + scol;
  const u16* Bg = Bt + (size_t)(tN + srow) * 1024 + scol;
  const int rs = (lr >> 1) & 3;

#define STAGE_OUT(buf, kk)                                                   \
  {                                                                          \
    GLD16(Ag + (size_t)(w * 16) * 1024 + (kk), &As[buf][(w * 16) * 32]);     \
    GLD16(Ag + (size_t)(64 + w * 16) * 1024 + (kk), &As[buf][(64 + w * 16) * 32]); \
    GLD16(Bg + (size_t)(w * 16) * 1024 + (kk), &Bs[buf][(w * 16) * 32]);     \
  }

  f32x4 acc[2][4] = {};
  STAGE_OUT(0, 0)
  __syncthreads();
  int cur = 0;
  for (int t = 0; t < 32; ++t) {
    if (t < 31) STAGE_OUT(cur ^ 1, (t + 1) * 32)
    const u16* Ac = &As[cur][0];
    const u16* Bc = &Bs[cur][0];
    bf16x8 a[2], b[4];
#pragma unroll
    for (int m = 0; m < 2; ++m)
      a[m] = *(const bf16x8*)(Ac + (w * 32 + m * 16 + lr) * 32 + ((lg ^ rs) << 3));
#pragma unroll
    for (int n = 0; n < 4; ++n)
      b[n] = *(const bf16x8*)(Bc + (n * 16 + lr) * 32 + ((lg ^ rs) << 3));
#pragma unroll
    for (int m = 0; m < 2; ++m)
#pragma unroll
      for (int n = 0; n < 4; ++n) acc[m][n] = MFMA(b[n], a[m], acc[m][n]);
    __syncthreads();
    cur ^= 1;
  }
#undef STAGE_OUT

#pragma unroll
  for (int m = 0; m < 2; ++m) {
    int s = tM + w * 32 + m * 16 + lr;
#pragma unroll
    for (int n = 0; n < 4; ++n) {
      int c = tN + n * 16 + lg * 4;
      float4 v;
      v.x = acc[m][n][0];
      v.y = acc[m][n][1];
      v.z = acc[m][n][2];
      v.w = acc[m][n][3];
      *(float4*)(out + (size_t)s * 1024 + c) = v;
    }
  }
}

extern "C" void kernel_launch(void* const* d_in, const int* in_sizes, int n_in,
                              void* d_out, int out_size, void* d_ws, size_t ws_size,
                              hipStream_t stream) {
  const float* X = (const float*)d_in[0];
  const float* Wq = (const float*)d_in[2];
  const float* Wk = (const float*)d_in[3];
  const float* Wv = (const float*)d_in[4];
  const float* Wo = (const float*)d_in[5];
  float* out = (float*)d_out;

  char* ws = (char*)d_ws;
  if (ws_size < (size_t)48 * 1024 * 1024) return;  // need 48 MiB scratch
  u16* Xb  = (u16*)(ws);                         // [4096][1024]   (dead after gemm_qkv)
  u16* Wt  = (u16*)(ws + 8388608);               // [3072][1024]   (dead after gemm_qkv)
  u16* Wot = (u16*)(ws + 14680064);              // [1024][1024]  Wo^T
  u16* Q   = (u16*)(ws + 16777216);              // [B,H,S,D] (pre-scaled, exp2 domain)
  u16* K   = (u16*)(ws + 25165824);              // [B,H,S,D]
  u16* Vt  = (u16*)(ws + 33554432);              // [B,H,D,S]  (transposed!)
  u16* AO  = (u16*)(ws + 41943040);              // [B,S,1024]
  // attention partials overlay the dead Xb/Wt regions:
  u16*   PO = (u16*)(ws);                        // [1024][64][64] bf16 unnormalized O
  float* ML = (float*)(ws + 8388608);            // [1024][2][64]  m,l (base-2)

  k_prep<<<6144, 256, 0, stream>>>(X, Wq, Wk, Wv, Wo, Xb, Wt, Wot);
  k_gemm_qkv<<<dim3(24, 32), 256, 0, stream>>>(Xb, Wt, Q, K, Vt);
  k_attn<<<1536, 256, 0, stream>>>(Q, K, Vt, AO, PO, ML);
  k_combine<<<512, 256, 0, stream>>>(PO, ML, AO);
  k_gemm_out<<<dim3(16, 32), 256, 0, stream>>>(AO, Wot, out);
}

// Round 18
// 116.629 us; speedup vs baseline: 1.0617x; 1.0617x over previous
//
#include <hip/hip_runtime.h>

typedef unsigned short u16;
typedef unsigned int u32;
typedef __bf16 bf16x8 __attribute__((ext_vector_type(8)));
typedef float f32x4 __attribute__((ext_vector_type(4)));

#define MFMA(a, b, c) __builtin_amdgcn_mfma_f32_16x16x32_bf16(a, b, c, 0, 0, 0)

#define GLD16(gsrc, ldst)                                                          \
  __builtin_amdgcn_global_load_lds(                                                \
      (const __attribute__((address_space(1))) void*)(gsrc),                       \
      (__attribute__((address_space(3))) void*)(ldst), 16, 0, 0)

#if __has_builtin(__builtin_amdgcn_exp2f)
#define EXP2(x) __builtin_amdgcn_exp2f(x)
#else
#define EXP2(x) exp2f(x)
#endif

// native RNE converts (compiler emits v_cvt_pk_bf16_f32 / scalar cvt)
__device__ __forceinline__ u16 f2bf(float f) {
  return __builtin_bit_cast(u16, (__bf16)f);
}

__device__ __forceinline__ u32 pk2(float a, float b) {
  __bf16 x = (__bf16)a, y = (__bf16)b;
  return (u32)__builtin_bit_cast(u16, x) | ((u32)__builtin_bit_cast(u16, y) << 16);
}

__device__ __forceinline__ float bf2f(u16 u) {
  return __builtin_bit_cast(float, ((u32)u) << 16);
}

// -------- fused prep: X fp32->bf16 convert  +  weight transpose/convert --------
__global__ __launch_bounds__(256) void k_prep(
    const float* __restrict__ X, const float* __restrict__ Wq,
    const float* __restrict__ Wk, const float* __restrict__ Wv,
    const float* __restrict__ Wo, u16* __restrict__ Xb,
    u16* __restrict__ Wt, u16* __restrict__ Wot) {
  __shared__ u16 t[32][33];
  int bid = blockIdx.x;
  if (bid < 2048) {
    int i = bid * 256 + threadIdx.x;
    const float4* p = (const float4*)X + (size_t)i * 2;
    float4 a = p[0], b = p[1];
    uint4 o;
    o.x = pk2(a.x, a.y);
    o.y = pk2(a.z, a.w);
    o.z = pk2(b.x, b.y);
    o.w = pk2(b.z, b.w);
    *(uint4*)(Xb + (size_t)i * 8) = o;
    return;
  }
  bid -= 2048;
  const int k0 = (bid & 31) * 32, n0 = (bid >> 5) * 32;
  const int x = threadIdx.x & 31, y = threadIdx.x >> 5;
  const float* src = (n0 < 1024) ? Wq : (n0 < 2048) ? Wk : (n0 < 3072) ? Wv : Wo;
  const int ncol = n0 & 1023;
#pragma unroll
  for (int rr = 0; rr < 4; ++rr) {
    int kl = y + rr * 8;
    t[x][kl] = f2bf(src[(size_t)(k0 + kl) * 1024 + ncol + x]);
  }
  __syncthreads();
  u16* dst = (n0 < 3072) ? (Wt + (size_t)n0 * 1024) : (Wot + (size_t)(n0 - 3072) * 1024);
#pragma unroll
  for (int rr = 0; rr < 4; ++rr) {
    int nl = y + rr * 8;
    dst[(size_t)nl * 1024 + k0 + x] = t[nl][x];
  }
}

// ============================================================================
// GEMM structure: BK=32, double-buffered LDS, ONE barrier per K-step (R6 proven).
// LDS tile [*][32] u16, 4 granules of 8 u16 per row.
// Swizzle: LDS slot s of row r holds global granule s ^ ((r>>1)&3).
// ============================================================================

// ---------------- QKV projection GEMM (R6 exact: 128x128) ----------------
// Q scaled by 0.125*log2(e) (exp2-domain softmax), layout [bh][s][d];
// K layout [bh][s][d]; V TRANSPOSED [bh][d][s]
__global__ __launch_bounds__(256) void k_gemm_qkv(const u16* __restrict__ A_,
                                                  const u16* __restrict__ Bt,
                                                  u16* __restrict__ Q,
                                                  u16* __restrict__ K,
                                                  u16* __restrict__ Vt) {
  __shared__ __align__(16) u16 As[2][128 * 32];
  __shared__ __align__(16) u16 Bs[2][128 * 32];
  const int tid = threadIdx.x;
  const int w = tid >> 6, l = tid & 63;
  const int lr = l & 15, lg = l >> 4;
  // XCD-aware swizzle (grid 24x32 = 768, 768%8==0 -> bijective)
  const int lin = blockIdx.y * 24 + blockIdx.x;
  const int swz = (lin & 7) * 96 + (lin >> 3);
  const int tM = (swz / 24) * 128, tN = (swz % 24) * 128;
  const int wr = w >> 1, wc = w & 1;
  const int bufsel = tN >> 10;  // 0=Q, 1=K, 2=V

  const int srow = l >> 2;
  const int scol = (((l & 3) ^ ((l >> 3) & 3)) << 3);  // pre-swizzled src granule
  const u16* Ag = A_ + (size_t)(tM + srow) * 1024 + scol;
  const u16* Bg = Bt + (size_t)(tN + srow) * 1024 + scol;
  const int rs = (lr >> 1) & 3;  // read-side swizzle

#define STAGE_QKV(buf, kk)                                                   \
  {                                                                          \
    GLD16(Ag + (size_t)(w * 16) * 1024 + (kk), &As[buf][(w * 16) * 32]);     \
    GLD16(Ag + (size_t)(64 + w * 16) * 1024 + (kk), &As[buf][(64 + w * 16) * 32]); \
    GLD16(Bg + (size_t)(w * 16) * 1024 + (kk), &Bs[buf][(w * 16) * 32]);     \
    GLD16(Bg + (size_t)(64 + w * 16) * 1024 + (kk), &Bs[buf][(64 + w * 16) * 32]); \
  }

  f32x4 acc[4][4] = {};
  STAGE_QKV(0, 0)
  __syncthreads();
  int cur = 0;

  if (bufsel < 2) {
    // ---- swapped-operand loop: acc rows = N(d)-dir via (lg,j), cols = M(s) via lr
    for (int t = 0; t < 32; ++t) {
      if (t < 31) STAGE_QKV(cur ^ 1, (t + 1) * 32)
      const u16* Ac = &As[cur][0];
      const u16* Bc = &Bs[cur][0];
      bf16x8 a[4], b[4];
#pragma unroll
      for (int m = 0; m < 4; ++m)
        a[m] = *(const bf16x8*)(Ac + (wr * 64 + m * 16 + lr) * 32 + ((lg ^ rs) << 3));
#pragma unroll
      for (int n = 0; n < 4; ++n)
        b[n] = *(const bf16x8*)(Bc + (wc * 64 + n * 16 + lr) * 32 + ((lg ^ rs) << 3));
#pragma unroll
      for (int m = 0; m < 4; ++m)
#pragma unroll
        for (int n = 0; n < 4; ++n) acc[m][n] = MFMA(b[n], a[m], acc[m][n]);
      __syncthreads();
      cur ^= 1;
    }
    u16* dst = bufsel ? K : Q;
    // 0.125 * log2(e): exp2-domain scores
    const float sc = bufsel ? 1.0f : 0.180336880111124f;
#pragma unroll
    for (int m = 0; m < 4; ++m) {
      int s = tM + wr * 64 + m * 16 + lr;
      int b_ = s >> 11, sr2 = s & 2047;
#pragma unroll
      for (int n = 0; n < 4; ++n) {
        int c2 = (tN + wc * 64 + n * 16 + lg * 4) & 1023;
        int h = c2 >> 6, d = c2 & 63;
        uint2 val;
        val.x = pk2(acc[m][n][0] * sc, acc[m][n][1] * sc);
        val.y = pk2(acc[m][n][2] * sc, acc[m][n][3] * sc);
        *(uint2*)(dst + ((size_t)(b_ * 16 + h) * 2048 + sr2) * 64 + d) = val;
      }
    }
  } else {
    // ---- normal loop: acc rows = M(s)-dir via (lg,j), cols = N(d) via lr
    for (int t = 0; t < 32; ++t) {
      if (t < 31) STAGE_QKV(cur ^ 1, (t + 1) * 32)
      const u16* Ac = &As[cur][0];
      const u16* Bc = &Bs[cur][0];
      bf16x8 a[4], b[4];
#pragma unroll
      for (int m = 0; m < 4; ++m)
        a[m] = *(const bf16x8*)(Ac + (wr * 64 + m * 16 + lr) * 32 + ((lg ^ rs) << 3));
#pragma unroll
      for (int n = 0; n < 4; ++n)
        b[n] = *(const bf16x8*)(Bc + (wc * 64 + n * 16 + lr) * 32 + ((lg ^ rs) << 3));
#pragma unroll
      for (int m = 0; m < 4; ++m)
#pragma unroll
        for (int n = 0; n < 4; ++n) acc[m][n] = MFMA(a[m], b[n], acc[m][n]);
      __syncthreads();
      cur ^= 1;
    }
    // V transposed: Vt[(bh*64 + d)][s], 4 consecutive s (=j) packed into 8B
#pragma unroll
    for (int m = 0; m < 4; ++m) {
      int r0 = tM + wr * 64 + m * 16 + lg * 4;
      int b_ = r0 >> 11, s0 = r0 & 2047;
#pragma unroll
      for (int n = 0; n < 4; ++n) {
        int c2 = (tN + wc * 64 + n * 16 + lr) & 1023;
        int h = c2 >> 6, d = c2 & 63;
        uint2 val;
        val.x = pk2(acc[m][n][0], acc[m][n][1]);
        val.y = pk2(acc[m][n][2], acc[m][n][3]);
        *(uint2*)(Vt + ((size_t)(b_ * 16 + h) * 64 + d) * 2048 + s0) = val;
      }
    }
  }
#undef STAGE_QKV
}

// ---------------- causal flash attention (KV-split flash-decode, R9 exact) ------
// 1536 blocks: (bh, qt, chunk). Chunks of <=16 K-tiles. qt<16: single chunk,
// final write. qt>=16: 2 chunks write unnormalized bf16 partials + m/l (base-2).
// Swapped QK^T AND swapped PV: softmax state + rescale fully lane-local (q=lr).
// Defer-max (T13) + setprio (T5).
__global__ __launch_bounds__(256, 4) void k_attn(const u16* __restrict__ Q,
                                                 const u16* __restrict__ Kg,
                                                 const u16* __restrict__ Vtg,
                                                 u16* __restrict__ AO,
                                                 u16* __restrict__ PO,
                                                 float* __restrict__ ML) {
  __shared__ __align__(16) u16 Ks[2][64 * 64];
  __shared__ __align__(16) u16 Vs[2][64 * 64];
  __shared__ __align__(16) u16 Ps[4][16 * 64];
  const int tid = threadIdx.x;
  const int w = tid >> 6, l = tid & 63;
  const int lr = l & 15, lg = l >> 4;

  const int idx = blockIdx.x;
  const int bh = idx & 31;
  const int g = idx >> 5;
  int qt, c0;
  if (g < 16) { qt = 16 + g; c0 = 0; }
  else if (g < 32) { qt = 31 - (g - 16); c0 = 1; }
  else { qt = 15 - (g - 32); c0 = 0; }
  const int nkt = (qt < 16) ? (qt + 1) : (c0 == 0 ? 16 : qt - 15);
  const bool hasdiag = (qt < 16) || (c0 == 1);
  const int q0 = qt * 64;

  const u16* Qp = Q + (size_t)bh * 2048 * 64;
  const u16* Kp = Kg + (size_t)bh * 2048 * 64;
  const u16* Vp = Vtg + (size_t)bh * 64 * 2048;

  const int qrow = q0 + w * 16 + lr;
  bf16x8 qa0 = *(const bf16x8*)(Qp + (size_t)qrow * 64 + lg * 8);
  bf16x8 qa1 = *(const bf16x8*)(Qp + (size_t)qrow * 64 + 32 + lg * 8);

  // oacc[n][j] = O[q = lr][d = n*16 + lg*4 + j]  (swapped-PV layout)
  f32x4 oacc[4] = {};
  float m_run = -1e30f, l_run = 0.f;

  const int srow = l >> 3;                // row-in-chunk 0..7
  const int scol = ((l & 7) ^ srow) * 8;  // pre-swizzled source column (u16)
  const int sw = (lr & 7) << 3;           // read-side swizzle (u16 units)

  // per-lane staging pointers (advance by one K-tile per iteration)
  const u16* kptr = Kp + ((size_t)c0 * 1024 + srow) * 64 + scol;
  const u16* vptr = Vp + (size_t)srow * 2048 + c0 * 1024 + scol;

  // prologue: stage tile 0 into buf 0
#pragma unroll
  for (int j = 0; j < 2; ++j) {
    int base = j * 32 + w * 8;
    GLD16(kptr + base * 64, &Ks[0][base * 64]);
    GLD16(vptr + (size_t)base * 2048, &Vs[0][base * 64]);
  }
  kptr += 4096;
  vptr += 64;
  __syncthreads();

  int cur = 0;

#define ATTN_TILE(DOPRE, DOMASK)                                                   \
  {                                                                                \
    if (DOPRE) {                                                                   \
      _Pragma("unroll") for (int j = 0; j < 2; ++j) {                              \
        int base = j * 32 + w * 8;                                                 \
        GLD16(kptr + base * 64, &Ks[cur ^ 1][base * 64]);                          \
        GLD16(vptr + (size_t)base * 2048, &Vs[cur ^ 1][base * 64]);                \
      }                                                                            \
      kptr += 4096;                                                                \
      vptr += 64;                                                                  \
    }                                                                              \
    f32x4 st[4];                                                                   \
    __builtin_amdgcn_s_setprio(1);                                                 \
    _Pragma("unroll") for (int n = 0; n < 4; ++n) {                                \
      const u16* kr = &Ks[cur][(n * 16 + lr) * 64];                                \
      bf16x8 kb0 = *(const bf16x8*)(kr + ((lg << 3) ^ sw));                        \
      bf16x8 kb1 = *(const bf16x8*)(kr + (((4 + lg) << 3) ^ sw));                  \
      f32x4 z = {0.f, 0.f, 0.f, 0.f};                                              \
      z = MFMA(kb0, qa0, z);                                                       \
      z = MFMA(kb1, qa1, z);                                                       \
      st[n] = z;                                                                   \
    }                                                                              \
    __builtin_amdgcn_s_setprio(0);                                                 \
    float mx = -1e30f;                                                             \
    _Pragma("unroll") for (int n = 0; n < 4; ++n)                                  \
        _Pragma("unroll") for (int j = 0; j < 4; ++j) {                            \
      float s = st[n][j];                                                          \
      if (DOMASK && (n * 16 + lg * 4 + j) > (w * 16 + lr)) s = -1e30f;             \
      st[n][j] = s;                                                                \
      mx = fmaxf(mx, s);                                                           \
    }                                                                              \
    mx = fmaxf(mx, __shfl_xor(mx, 16, 64));                                        \
    mx = fmaxf(mx, __shfl_xor(mx, 32, 64));                                        \
    const bool grow = __any(mx > m_run + 8.0f);  /* defer-max THR=8 */             \
    float mnew = grow ? fmaxf(m_run, mx) : m_run;                                  \
    float rsum = 0.f;                                                              \
    _Pragma("unroll") for (int n = 0; n < 4; ++n)                                  \
        _Pragma("unroll") for (int j = 0; j < 4; ++j) {                            \
      float p = EXP2(st[n][j] - mnew);                                             \
      st[n][j] = p;                                                                \
      rsum += p;                                                                   \
    }                                                                              \
    rsum += __shfl_xor(rsum, 16, 64);                                              \
    rsum += __shfl_xor(rsum, 32, 64);                                              \
    if (grow) {                                                                    \
      float fsc = EXP2(m_run - mnew);                                              \
      l_run = l_run * fsc + rsum;                                                  \
      m_run = mnew;                                                                \
      _Pragma("unroll") for (int n = 0; n < 4; ++n)                                \
          _Pragma("unroll") for (int j = 0; j < 4; ++j) oacc[n][j] *= fsc;         \
    } else {                                                                       \
      l_run += rsum;                                                               \
    }                                                                              \
    u16* pb = &Ps[w][0];                                                           \
    _Pragma("unroll") for (int n = 0; n < 4; ++n) {                                \
      int slot = n * 2 + (lg >> 1);                                                \
      int off = lr * 64 + ((slot ^ (lr & 7)) << 3) + (lg & 1) * 4;                 \
      uint2 val;                                                                   \
      val.x = pk2(st[n][0], st[n][1]);                                             \
      val.y = pk2(st[n][2], st[n][3]);                                             \
      *(uint2*)(pb + off) = val;                                                   \
    }                                                                              \
    bf16x8 pa0 = *(const bf16x8*)(pb + lr * 64 + ((lg << 3) ^ sw));                \
    bf16x8 pa1 = *(const bf16x8*)(pb + lr * 64 + (((4 + lg) << 3) ^ sw));          \
    __builtin_amdgcn_s_setprio(1);                                                 \
    _Pragma("unroll") for (int n = 0; n < 4; ++n) {                                \
      const u16* vr = &Vs[cur][(n * 16 + lr) * 64];                                \
      bf16x8 vb0 = *(const bf16x8*)(vr + ((lg << 3) ^ sw));                        \
      bf16x8 vb1 = *(const bf16x8*)(vr + (((4 + lg) << 3) ^ sw));                  \
      oacc[n] = MFMA(vb0, pa0, oacc[n]);                                           \
      oacc[n] = MFMA(vb1, pa1, oacc[n]);                                           \
    }                                                                              \
    __builtin_amdgcn_s_setprio(0);                                                 \
  }

  // main loop: no masking, always prefetch
  for (int it = 0; it < nkt - 1; ++it) {
    ATTN_TILE(true, false);
    __syncthreads();
    cur ^= 1;
  }
  // tail: no prefetch; mask only if this chunk contains the diagonal
  if (hasdiag) {
    ATTN_TILE(false, true);
  } else {
    ATTN_TILE(false, false);
  }
#undef ATTN_TILE

  if (qt < 16) {
    const int b_ = bh >> 4, h = bh & 15;
    const float linv = 1.0f / l_run;  // lane-local (q = lr)
    const int s = q0 + w * 16 + lr;
    u16* dst = AO + ((size_t)(b_ * 2048 + s)) * 1024 + h * 64 + lg * 4;
#pragma unroll
    for (int n = 0; n < 4; ++n) {
      uint2 val;
      val.x = pk2(oacc[n][0] * linv, oacc[n][1] * linv);
      val.y = pk2(oacc[n][2] * linv, oacc[n][3] * linv);
      *(uint2*)(dst + n * 16) = val;
    }
  } else {
    const int p = (bh * 16 + (qt - 16)) * 2 + c0;
    u16* po = PO + (size_t)p * 4096 + (size_t)(w * 16 + lr) * 64 + lg * 4;
#pragma unroll
    for (int n = 0; n < 4; ++n) {
      uint2 val;
      val.x = pk2(oacc[n][0], oacc[n][1]);
      val.y = pk2(oacc[n][2], oacc[n][3]);
      *(uint2*)(po + n * 16) = val;
    }
    if (lg == 0) {
      ML[(size_t)p * 128 + (w * 16 + lr)] = m_run;
      ML[(size_t)p * 128 + 64 + (w * 16 + lr)] = l_run;
    }
  }
}

// ---------------- combine partials for qt >= 16 (base-2 m/l) ----------------
__global__ __launch_bounds__(256) void k_combine(const u16* __restrict__ PO,
                                                 const float* __restrict__ ML,
                                                 u16* __restrict__ AO) {
  const int blk = blockIdx.x;  // bh*16 + (qt-16)
  const int bh = blk >> 4, qt = 16 + (blk & 15);
  const int row = threadIdx.x >> 2;
  const int dseg = (threadIdx.x & 3) * 16;
  const size_t p0 = (size_t)blk * 2;
  const float m0 = ML[p0 * 128 + row], l0 = ML[p0 * 128 + 64 + row];
  const float m1 = ML[p0 * 128 + 128 + row], l1 = ML[p0 * 128 + 192 + row];
  const float M = fmaxf(m0, m1);
  float w0 = EXP2(m0 - M), w1 = EXP2(m1 - M);
  const float inv = 1.0f / (l0 * w0 + l1 * w1);
  w0 *= inv;
  w1 *= inv;
  const u16* o0 = PO + p0 * 4096 + (size_t)row * 64 + dseg;
  const u16* o1 = o0 + 4096;
  const int b_ = bh >> 4, h = bh & 15;
  u16* dst = AO + ((size_t)(b_ * 2048 + qt * 64 + row)) * 1024 + h * 64 + dseg;
#pragma unroll
  for (int half = 0; half < 2; ++half) {
    uint4 a = *(const uint4*)(o0 + half * 8);
    uint4 b = *(const uint4*)(o1 + half * 8);
    u32 aw[4] = {a.x, a.y, a.z, a.w};
    u32 bw[4] = {b.x, b.y, b.z, b.w};
    uint4 o;
    u32 ow[4];
#pragma unroll
    for (int i = 0; i < 4; ++i) {
      float r0 = bf2f((u16)(aw[i] & 0xffffu)) * w0 + bf2f((u16)(bw[i] & 0xffffu)) * w1;
      float r1 = bf2f((u16)(aw[i] >> 16)) * w0 + bf2f((u16)(bw[i] >> 16)) * w1;
      ow[i] = pk2(r0, r1);
    }
    o.x = ow[0]; o.y = ow[1]; o.z = ow[2]; o.w = ow[3];
    *(uint4*)(dst + half * 8) = o;
  }
}

// ---------------- output projection GEMM (fp32 out) ----------------
// 128x64 tiles, BK=32 dbuf, swapped operands -> float4 stores (R6 proven).
__global__ __launch_bounds__(256) void k_gemm_out(const u16* __restrict__ A_,
                                                  const u16* __restrict__ Bt,
                                                  float* __restrict__ out) {
  __shared__ __align__(16) u16 As[2][128 * 32];
  __shared__ __align__(16) u16 Bs[2][64 * 32];
  const int tid = threadIdx.x;
  const int w = tid >> 6, l = tid & 63;
  const int lr = l & 15, lg = l >> 4;
  // XCD swizzle (grid 16x32 = 512)
  const int lin = blockIdx.y * 16 + blockIdx.x;
  const int swz = (lin & 7) * 64 + (lin >> 3);
  const int tM = (swz / 16) * 128, tN = (swz % 16) * 64;

  const int srow = l >> 2;
  const int scol = (((l & 3) ^ ((l >> 3) & 3)) << 3);
  const u16* Ag = A_ + (size_t)(tM + srow) * 1024 + scol;
  const u16* Bg = Bt + (size_t)(tN + srow) * 1024 + scol;
  const int rs = (lr >> 1) & 3;

#define STAGE_OUT(buf, kk)                                                   \
  {                                                                          \
    GLD16(Ag + (size_t)(w * 16) * 1024 + (kk), &As[buf][(w * 16) * 32]);     \
    GLD16(Ag + (size_t)(64 + w * 16) * 1024 + (kk), &As[buf][(64 + w * 16) * 32]); \
    GLD16(Bg + (size_t)(w * 16) * 1024 + (kk), &Bs[buf][(w * 16) * 32]);     \
  }

  f32x4 acc[2][4] = {};
  STAGE_OUT(0, 0)
  __syncthreads();
  int cur = 0;
  for (int t = 0; t < 32; ++t) {
    if (t < 31) STAGE_OUT(cur ^ 1, (t + 1) * 32)
    const u16* Ac = &As[cur][0];
    const u16* Bc = &Bs[cur][0];
    bf16x8 a[2], b[4];
#pragma unroll
    for (int m = 0; m < 2; ++m)
      a[m] = *(const bf16x8*)(Ac + (w * 32 + m * 16 + lr) * 32 + ((lg ^ rs) << 3));
#pragma unroll
    for (int n = 0; n < 4; ++n)
      b[n] = *(const bf16x8*)(Bc + (n * 16 + lr) * 32 + ((lg ^ rs) << 3));
#pragma unroll
    for (int m = 0; m < 2; ++m)
#pragma unroll
      for (int n = 0; n < 4; ++n) acc[m][n] = MFMA(b[n], a[m], acc[m][n]);
    __syncthreads();
    cur ^= 1;
  }
#undef STAGE_OUT

#pragma unroll
  for (int m = 0; m < 2; ++m) {
    int s = tM + w * 32 + m * 16 + lr;
#pragma unroll
    for (int n = 0; n < 4; ++n) {
      int c = tN + n * 16 + lg * 4;
      float4 v;
      v.x = acc[m][n][0];
      v.y = acc[m][n][1];
      v.z = acc[m][n][2];
      v.w = acc[m][n][3];
      *(float4*)(out + (size_t)s * 1024 + c) = v;
    }
  }
}

extern "C" void kernel_launch(void* const* d_in, const int* in_sizes, int n_in,
                              void* d_out, int out_size, void* d_ws, size_t ws_size,
                              hipStream_t stream) {
  const float* X = (const float*)d_in[0];
  const float* Wq = (const float*)d_in[2];
  const float* Wk = (const float*)d_in[3];
  const float* Wv = (const float*)d_in[4];
  const float* Wo = (const float*)d_in[5];
  float* out = (float*)d_out;

  char* ws = (char*)d_ws;
  if (ws_size < (size_t)48 * 1024 * 1024) return;  // need 48 MiB scratch
  u16* Xb  = (u16*)(ws);                         // [4096][1024]   (dead after gemm_qkv)
  u16* Wt  = (u16*)(ws + 8388608);               // [3072][1024]   (dead after gemm_qkv)
  u16* Wot = (u16*)(ws + 14680064);              // [1024][1024]  Wo^T
  u16* Q   = (u16*)(ws + 16777216);              // [B,H,S,D] (pre-scaled, exp2 domain)
  u16* K   = (u16*)(ws + 25165824);              // [B,H,S,D]
  u16* Vt  = (u16*)(ws + 33554432);              // [B,H,D,S]  (transposed!)
  u16* AO  = (u16*)(ws + 41943040);              // [B,S,1024]
  // attention partials overlay the dead Xb/Wt regions:
  u16*   PO = (u16*)(ws);                        // [1024][64][64] bf16 unnormalized O
  float* ML = (float*)(ws + 8388608);            // [1024][2][64]  m,l (base-2)

  k_prep<<<6144, 256, 0, stream>>>(X, Wq, Wk, Wv, Wo, Xb, Wt, Wot);
  k_gemm_qkv<<<dim3(24, 32), 256, 0, stream>>>(Xb, Wt, Q, K, Vt);
  k_attn<<<1536, 256, 0, stream>>>(Q, K, Vt, AO, PO, ML);
  k_combine<<<512, 256, 0, stream>>>(PO, ML, AO);
  k_gemm_out<<<dim3(16, 32), 256, 0, stream>>>(AO, Wot, out);
}